// Round 10
// baseline (3399.297 us; speedup 1.0000x reference)
//
#include <hip/hip_runtime.h>
#include <hip/hip_bf16.h>
#include <math.h>

// Problem constants
#define NFE 17      // graph nodes (features)
#define T2V 16      // time2vec dim
#define D0C 34      // 2 + 2*T2V
#define BB 128      // batch
#define TT 256      // seq len
#define HH 128      // GRU hidden
#define PSTR 132    // padded row stride; 132*4B=528B=33*16 -> every row 16B aligned

typedef __hip_bfloat16 bf16;
__device__ __forceinline__ float b2f(bf16 x) { return __bfloat162float(x); }

// fast transcendentals (native v_exp_f32/v_sin_f32; ~2ulp)
__device__ __forceinline__ float elu_fast(float v)  { return v > 0.f ? v : __expf(v) - 1.f; }
__device__ __forceinline__ float sigm_fast(float x) { return __fdividef(1.f, 1.f + __expf(-x)); }
__device__ __forceinline__ float tanh_fast(float x) {
  return __fdividef(2.f, 1.f + __expf(-2.f*x)) - 1.f;
}

// ---------------- GAT building blocks (per-graph, LDS resident) ----------------

// layer-0 proj (17% of MACs): rows {ty,ty+8,16(pred)}, 4 cols, STEP=2 (R7-proven)
template<int D, int SSTR, int STEP>
__device__ __forceinline__ void gat_proj_rb(const float* s_src,
                                            const float* __restrict__ W,
                                            float* s_dst, int tid) {
  const int tx = (tid & 31) * 4, ty = tid >> 5;
  float acc[3][4];
  #pragma unroll
  for (int i = 0; i < 3; ++i)
    #pragma unroll
    for (int c = 0; c < 4; ++c) acc[i][c] = 0.f;
  float4 wbuf[STEP];
  #pragma unroll
  for (int s = 0; s < STEP; ++s)
    wbuf[s] = *(const float4*)&W[s*128 + tx];
  for (int d0 = 0; d0 < D; d0 += STEP) {
    float4 wcur[STEP];
    #pragma unroll
    for (int s = 0; s < STEP; ++s) wcur[s] = wbuf[s];
    if (d0 + STEP < D) {
      #pragma unroll
      for (int s = 0; s < STEP; ++s)
        wbuf[s] = *(const float4*)&W[(d0 + STEP + s)*128 + tx];
    }
    float sv[3][STEP];
    #pragma unroll
    for (int i = 0; i < 3; ++i) {
      const int r = ty + 8*i;
      if (i < 2 || ty == 0) {
        #pragma unroll
        for (int s = 0; s < STEP; ++s) sv[i][s] = s_src[r*SSTR + d0 + s];
      }
    }
    #pragma unroll
    for (int s = 0; s < STEP; ++s) {
      #pragma unroll
      for (int i = 0; i < 3; ++i) {
        if (i < 2 || ty == 0) {
          acc[i][0] = fmaf(sv[i][s], wcur[s].x, acc[i][0]);
          acc[i][1] = fmaf(sv[i][s], wcur[s].y, acc[i][1]);
          acc[i][2] = fmaf(sv[i][s], wcur[s].z, acc[i][2]);
          acc[i][3] = fmaf(sv[i][s], wcur[s].w, acc[i][3]);
        }
      }
    }
  }
  #pragma unroll
  for (int i = 0; i < 3; ++i) {
    const int r = ty + 8*i;
    if (i < 2 || ty == 0) {
      #pragma unroll
      for (int c = 0; c < 4; ++c) s_dst[r*PSTR + tx + c] = acc[i][c];
    }
  }
}

// layer-1 proj (63% of MACs): copy-free ping-pong double buffer (R9-proven).
__device__ __forceinline__ void gat_proj128_db(const float* s_src,
                                               const float* __restrict__ W,
                                               float* s_dst, int tid) {
  const int tx = (tid & 31) * 4, ty = tid >> 5;
  const int r0 = ty, r1 = ty + 8;
  float a0[4] = {0.f,0.f,0.f,0.f}, a1[4] = {0.f,0.f,0.f,0.f}, a2[4] = {0.f,0.f,0.f,0.f};
  float4 wA[4], wB[4];
  #pragma unroll
  for (int s = 0; s < 4; ++s) wA[s] = *(const float4*)&W[s*128 + tx];
  #pragma unroll 1
  for (int d0 = 0; d0 < 128; d0 += 8) {
    #pragma unroll
    for (int s = 0; s < 4; ++s) wB[s] = *(const float4*)&W[(d0 + 4 + s)*128 + tx];
    float sv0[4], sv1[4], sv2[4];
    *(float4*)sv0 = *(const float4*)&s_src[r0*PSTR + d0];
    *(float4*)sv1 = *(const float4*)&s_src[r1*PSTR + d0];
    if (ty == 0) *(float4*)sv2 = *(const float4*)&s_src[16*PSTR + d0];
    #pragma unroll
    for (int s = 0; s < 4; ++s) {
      const float4 w4 = wA[s];
      a0[0] = fmaf(sv0[s], w4.x, a0[0]); a0[1] = fmaf(sv0[s], w4.y, a0[1]);
      a0[2] = fmaf(sv0[s], w4.z, a0[2]); a0[3] = fmaf(sv0[s], w4.w, a0[3]);
      a1[0] = fmaf(sv1[s], w4.x, a1[0]); a1[1] = fmaf(sv1[s], w4.y, a1[1]);
      a1[2] = fmaf(sv1[s], w4.z, a1[2]); a1[3] = fmaf(sv1[s], w4.w, a1[3]);
      if (ty == 0) {
        a2[0] = fmaf(sv2[s], w4.x, a2[0]); a2[1] = fmaf(sv2[s], w4.y, a2[1]);
        a2[2] = fmaf(sv2[s], w4.z, a2[2]); a2[3] = fmaf(sv2[s], w4.w, a2[3]);
      }
    }
    if (d0 + 8 < 128) {
      #pragma unroll
      for (int s = 0; s < 4; ++s) wA[s] = *(const float4*)&W[(d0 + 8 + s)*128 + tx];
    }
    *(float4*)sv0 = *(const float4*)&s_src[r0*PSTR + d0 + 4];
    *(float4*)sv1 = *(const float4*)&s_src[r1*PSTR + d0 + 4];
    if (ty == 0) *(float4*)sv2 = *(const float4*)&s_src[16*PSTR + d0 + 4];
    #pragma unroll
    for (int s = 0; s < 4; ++s) {
      const float4 w4 = wB[s];
      a0[0] = fmaf(sv0[s], w4.x, a0[0]); a0[1] = fmaf(sv0[s], w4.y, a0[1]);
      a0[2] = fmaf(sv0[s], w4.z, a0[2]); a0[3] = fmaf(sv0[s], w4.w, a0[3]);
      a1[0] = fmaf(sv1[s], w4.x, a1[0]); a1[1] = fmaf(sv1[s], w4.y, a1[1]);
      a1[2] = fmaf(sv1[s], w4.z, a1[2]); a1[3] = fmaf(sv1[s], w4.w, a1[3]);
      if (ty == 0) {
        a2[0] = fmaf(sv2[s], w4.x, a2[0]); a2[1] = fmaf(sv2[s], w4.y, a2[1]);
        a2[2] = fmaf(sv2[s], w4.z, a2[2]); a2[3] = fmaf(sv2[s], w4.w, a2[3]);
      }
    }
  }
  #pragma unroll
  for (int c = 0; c < 4; ++c) {
    s_dst[r0*PSTR + tx + c] = a0[c];
    s_dst[r1*PSTR + tx + c] = a1[c];
  }
  if (ty == 0) {
    #pragma unroll
    for (int c = 0; c < 4; ++c) s_dst[16*PSTR + tx + c] = a2[c];
  }
}

__device__ __forceinline__ void gat_scores(const float* s_p,
                                           const float* __restrict__ asrc,
                                           const float* __restrict__ adst,
                                           float* s_es, float* s_ed, int tid) {
  if (tid < 2*4*NFE) {                 // 136 threads: 68 for es, 68 for ed
    const int which = tid >= 4*NFE;
    const int r = which ? tid - 4*NFE : tid;
    const int h = r / NFE, f = r - h*NFE;
    const float* av = which ? adst : asrc;
    float acc = 0.f;
    #pragma unroll
    for (int o = 0; o < 32; ++o)
      acc = fmaf(s_p[f*PSTR + h*32 + o], av[h*32 + o], acc);
    (which ? s_ed : s_es)[h*NFE + f] = acc;
  }
}

__device__ __forceinline__ void gat_softmax(const float* s_es, const float* s_ed,
                                            const float* s_adj,
                                            float* s_e, int tid) {
  if (tid < 4*NFE) {                   // one thread per (head,row)
    const int h = tid / NFE, i = tid - h*NFE;
    float row[NFE]; float mx = -1e30f;
    #pragma unroll
    for (int j = 0; j < NFE; ++j) {
      float v = -1.0e9f;
      if (s_adj[i*NFE + j] > 0.f) {
        float e = s_es[h*NFE + i] + s_ed[h*NFE + j];
        v = (e > 0.f) ? e : 0.2f*e;    // leaky_relu 0.2
      }
      row[j] = v; mx = fmaxf(mx, v);
    }
    float sum = 0.f;
    #pragma unroll
    for (int j = 0; j < NFE; ++j) { row[j] = __expf(row[j] - mx); sum += row[j]; }
    const float inv = __fdividef(1.f, sum);
    #pragma unroll
    for (int j = 0; j < NFE; ++j) s_e[(h*NFE + i)*NFE + j] = row[j]*inv;
  }
}

// layer-0 out: full store to s_dst (needed as residual + proj input)
__device__ __forceinline__ void gat_out_rb(const float* s_e, const float* s_p,
                                           const float* s_res, float* s_dst, int tid) {
  const int tx = (tid & 31) * 4, ty = tid >> 5;
  const int h = tx >> 5;               // 4 cols always within one head
  float acc[3][4];
  #pragma unroll
  for (int i = 0; i < 3; ++i)
    #pragma unroll
    for (int c = 0; c < 4; ++c) acc[i][c] = 0.f;
  for (int j = 0; j < NFE; ++j) {
    const float4 pv = *(const float4*)&s_p[j*PSTR + tx];
    #pragma unroll
    for (int i = 0; i < 3; ++i) {
      const int r = ty + 8*i;
      if (i < 2 || ty == 0) {
        const float av = s_e[(h*NFE + r)*NFE + j];
        acc[i][0] = fmaf(av, pv.x, acc[i][0]);
        acc[i][1] = fmaf(av, pv.y, acc[i][1]);
        acc[i][2] = fmaf(av, pv.z, acc[i][2]);
        acc[i][3] = fmaf(av, pv.w, acc[i][3]);
      }
    }
  }
  #pragma unroll
  for (int i = 0; i < 3; ++i) {
    const int r = ty + 8*i;
    if (i < 2 || ty == 0) {
      #pragma unroll
      for (int c = 0; c < 4; ++c) {
        float v = acc[i][c] + (s_res ? s_res[r*PSTR + tx + c] : 0.f);
        s_dst[r*PSTR + tx + c] = elu_fast(v);
      }
    }
  }
}

// layer-1 out: no s_o store — per-thread column partial sums over its rows.
// psum[c] = sum over rows {ty, ty+8, 16(ty==0)} of elu(acc + res).
__device__ __forceinline__ void gat_out_psum(const float* s_e, const float* s_p,
                                             const float* s_res, float* psum, int tid) {
  const int tx = (tid & 31) * 4, ty = tid >> 5;
  const int h = tx >> 5;
  float acc[3][4];
  #pragma unroll
  for (int i = 0; i < 3; ++i)
    #pragma unroll
    for (int c = 0; c < 4; ++c) acc[i][c] = 0.f;
  for (int j = 0; j < NFE; ++j) {
    const float4 pv = *(const float4*)&s_p[j*PSTR + tx];
    #pragma unroll
    for (int i = 0; i < 3; ++i) {
      const int r = ty + 8*i;
      if (i < 2 || ty == 0) {
        const float av = s_e[(h*NFE + r)*NFE + j];
        acc[i][0] = fmaf(av, pv.x, acc[i][0]);
        acc[i][1] = fmaf(av, pv.y, acc[i][1]);
        acc[i][2] = fmaf(av, pv.z, acc[i][2]);
        acc[i][3] = fmaf(av, pv.w, acc[i][3]);
      }
    }
  }
  #pragma unroll
  for (int c = 0; c < 4; ++c) psum[c] = 0.f;
  #pragma unroll
  for (int i = 0; i < 3; ++i) {
    const int r = ty + 8*i;
    if (i < 2 || ty == 0) {
      #pragma unroll
      for (int c = 0; c < 4; ++c)
        psum[c] += elu_fast(acc[i][c] + s_res[r*PSTR + tx + c]);
    }
  }
}

// --------------- fused featurize + GAT0 + GAT1 + node-mean -------------------
// launch_bounds(256,5): LDS ~30.9KB -> 5 blocks/CU; VGPR cap 512/5=102 (need ~80)
__global__ __launch_bounds__(256, 5) void gat_fused(
    const float* __restrict__ X,  const float* __restrict__ Mk,
    const float* __restrict__ Dl, const float* __restrict__ Tm,
    const float* __restrict__ Adj,
    const float* __restrict__ aw0, const float* __restrict__ ab0,
    const float* __restrict__ aW,  const float* __restrict__ aB,
    const float* __restrict__ dw0, const float* __restrict__ db0,
    const float* __restrict__ dW,  const float* __restrict__ dB,
    const float* __restrict__ W0,  const float* __restrict__ as0,
    const float* __restrict__ ad0, const float* __restrict__ W1,
    const float* __restrict__ as1, const float* __restrict__ ad1,
    float* __restrict__ zslot)         // [B*T][256], z goes in cols 128..255
{
  __shared__ float s_nf[NFE*D0C];
  __shared__ __align__(16) float s_p [NFE*PSTR];
  __shared__ __align__(16) float s_h [NFE*PSTR];
  __shared__ __align__(16) float s_red[8*128];   // layer-1 mean partials
  __shared__ float s_e [4*NFE*NFE];
  __shared__ float s_es[4*NFE];
  __shared__ float s_ed[4*NFE];
  __shared__ float s_t [T2V];
  __shared__ float s_adj[NFE*NFE];
  const int n = blockIdx.x;            // n = b*T + t  (matches times layout)
  const int tid = threadIdx.x;

  const float tv = Tm[n];
  if (tid < T2V) {
    s_t[tid] = (tid == 0) ? fmaf(tv, aw0[0], ab0[0])
                          : __sinf(fmaf(tv, aW[tid-1], aB[tid-1]));
  }
  for (int idx = tid; idx < NFE*NFE; idx += 256) s_adj[idx] = Adj[idx];
  __syncthreads();
  // node features: [X, mask, t_emb(16), d_emb(16)]
  for (int idx = tid; idx < NFE*D0C; idx += 256) {
    const int f = idx / D0C, c = idx - f*D0C;
    float v;
    if (c == 0)            v = X [(size_t)n*NFE + f];
    else if (c == 1)       v = Mk[(size_t)n*NFE + f];
    else if (c < 2 + T2V)  v = s_t[c-2];
    else {
      const float dd = Dl[(size_t)n*NFE + f];
      const int j = c - (2 + T2V);
      v = (j == 0) ? fmaf(dd, dw0[0], db0[0])
                   : __sinf(fmaf(dd, dW[j-1], dB[j-1]));
    }
    s_nf[idx] = v;
  }
  __syncthreads();
  // GAT layer 0 (no residual)
  gat_proj_rb<D0C, D0C, 2>(s_nf, W0, s_p, tid);    __syncthreads();
  gat_scores(s_p, as0, ad0, s_es, s_ed, tid);      __syncthreads();
  gat_softmax(s_es, s_ed, s_adj, s_e, tid);        __syncthreads();
  gat_out_rb(s_e, s_p, nullptr, s_h, tid);         __syncthreads();
  // GAT layer 1 (residual) -> direct node-mean, no s_o
  gat_proj128_db(s_h, W1, s_p, tid);               __syncthreads();
  gat_scores(s_p, as1, ad1, s_es, s_ed, tid);      __syncthreads();
  gat_softmax(s_es, s_ed, s_adj, s_e, tid);        __syncthreads();
  {
    float psum[4];
    gat_out_psum(s_e, s_p, s_h, psum, tid);
    const int tx = (tid & 31) * 4, ty = tid >> 5;
    *(float4*)&s_red[ty*128 + tx] = *(float4*)psum;
    __syncthreads();
    if (tid < 128) {
      float acc = 0.f;
      #pragma unroll
      for (int k = 0; k < 8; ++k) acc += s_red[k*128 + tid];
      zslot[(size_t)n*256 + 128 + tid] = acc * (1.0f/17.0f);
    }
  }
}

// ------- GEMM: C[M,384] = A[M,K](f32, row pitch lda) * W[384,K](f32)^T + bias
// C stored bf16 (gate pre-activations; rel err 2^-9 << harness bf16 floor)
__global__ __launch_bounds__(256) void gemm_xw_bias(
    const float* __restrict__ A, int lda, const float* __restrict__ W,
    const float* __restrict__ bias, bf16* __restrict__ C, int K)
{
  __shared__ float As[16][68];   // +4 pad
  __shared__ float Ws[16][68];
  const int tid = threadIdx.x;
  const int bm0 = blockIdx.x * 64;
  const int bn0 = blockIdx.y * 64;
  const int tx = tid & 15, ty = tid >> 4;
  float acc[4][4];
  #pragma unroll
  for (int i = 0; i < 4; ++i)
    #pragma unroll
    for (int j = 0; j < 4; ++j) acc[i][j] = 0.f;
  for (int kk = 0; kk < K; kk += 16) {
    #pragma unroll
    for (int l = 0; l < 4; ++l) {
      const int lin = tid + l*256;
      const int r = lin >> 4, k = lin & 15;
      As[k][r] = A[(size_t)(bm0 + r)*lda + kk + k];
      Ws[k][r] = W[(size_t)(bn0 + r)*K + kk + k];
    }
    __syncthreads();
    #pragma unroll
    for (int k = 0; k < 16; ++k) {
      float av[4], wv[4];
      #pragma unroll
      for (int i = 0; i < 4; ++i) av[i] = As[k][ty*4 + i];
      #pragma unroll
      for (int j = 0; j < 4; ++j) wv[j] = Ws[k][tx*4 + j];
      #pragma unroll
      for (int i = 0; i < 4; ++i)
        #pragma unroll
        for (int j = 0; j < 4; ++j) acc[i][j] = fmaf(av[i], wv[j], acc[i][j]);
    }
    __syncthreads();
  }
  float bv[4];
  #pragma unroll
  for (int j = 0; j < 4; ++j) bv[j] = bias[bn0 + tx*4 + j];
  #pragma unroll
  for (int i = 0; i < 4; ++i)
    #pragma unroll
    for (int j = 0; j < 4; ++j)
      C[(size_t)(bm0 + ty*4 + i)*384 + bn0 + tx*4 + j] =
          __float2bfloat16(acc[i][j] + bv[j]);
}

// ---------------- GRU recurrence: one block per (dir, batch-row) -------------
__global__ __launch_bounds__(384, 1) void gru_rec(
    const bf16* __restrict__ gxf,      // [B][T][384] forward-dir input proj
    const bf16* __restrict__ gxb,      // [B][T][384] backward-dir input proj
    const float* __restrict__ whh_f, const float* __restrict__ whh_b,
    const float* __restrict__ bhh_f, const float* __restrict__ bhh_b,
    float* __restrict__ ys,            // [B][T][256], dir*128 col offset
    float* __restrict__ hfin)          // layer1: patient_emb f32 (or null)
{
  const int blk = blockIdx.x;
  const int dir = blk >> 7;
  const int b   = blk & 127;
  const int g   = threadIdx.x;
  const float* whh = dir ? whh_b : whh_f;
  const float* bhh = dir ? bhh_b : bhh_f;
  const bf16* gx   = (dir ? gxb : gxf) + (size_t)b*TT*384;
  __shared__ __align__(16) float s_h[HH];
  __shared__ float s_gh[3*HH];
  __shared__ float s_gx[3*HH];
  float4 w[HH/4];
  #pragma unroll
  for (int d4 = 0; d4 < HH/4; ++d4)
    w[d4] = *(const float4*)&whh[(size_t)g*HH + 4*d4];
  const float bh = bhh[g];
  float hreg = 0.f;
  if (g < HH) s_h[g] = 0.f;
  __syncthreads();
  for (int s = 0; s < TT; ++s) {
    const int t = dir ? (TT-1-s) : s;
    const float gxv = b2f(gx[(size_t)t*384 + g]);
    float acc = bh;
    const float4* h4 = (const float4*)s_h;
    #pragma unroll
    for (int d4 = 0; d4 < HH/4; ++d4) {
      const float4 hv = h4[d4];
      acc = fmaf(hv.x, w[d4].x, acc);
      acc = fmaf(hv.y, w[d4].y, acc);
      acc = fmaf(hv.z, w[d4].z, acc);
      acc = fmaf(hv.w, w[d4].w, acc);
    }
    s_gh[g] = acc;     // gh (incl. bhh)
    s_gx[g] = gxv;     // gx (incl. bih)
    __syncthreads();   // all dot-reads of s_h complete; s_gh/s_gx visible
    if (g < HH) {
      const float r  = sigm_fast(s_gx[g]    + s_gh[g]);
      const float zg = sigm_fast(s_gx[HH+g] + s_gh[HH+g]);
      const float nn = tanh_fast(s_gx[2*HH+g] + r*s_gh[2*HH+g]);
      hreg = (1.f - zg)*nn + zg*hreg;
      s_h[g] = hreg;
      ys[((size_t)b*TT + t)*256 + dir*HH + g] = hreg;
    }
    __syncthreads();   // new s_h visible before next step's dot
  }
  if (g < HH && hfin) hfin[(size_t)b*256 + dir*HH + g] = hreg;
}

// ---------------- heads ------------------------------------------------------
__global__ __launch_bounds__(64) void heads_k(
    const float* __restrict__ pemb,
    const float* __restrict__ mw1, const float* __restrict__ mb1,
    const float* __restrict__ mw2, const float* __restrict__ mb2,
    const float* __restrict__ cw1, const float* __restrict__ cb1,
    const float* __restrict__ cw2, const float* __restrict__ cb2,
    float* __restrict__ out)
{
  const int b = blockIdx.x, tid = threadIdx.x;
  __shared__ float sh[64];
  const float* pe = pemb + (size_t)b*256;
  float acc = mb1[tid];
  for (int d = 0; d < 256; ++d) acc = fmaf(pe[d], mw1[(size_t)tid*256 + d], acc);
  sh[tid] = fmaxf(acc, 0.f) * mw2[tid];
  __syncthreads();
  if (tid == 0) {
    float s = mb2[0];
    for (int i = 0; i < 64; ++i) s += sh[i];
    out[b]       = s;
    out[128 + b] = 1.f/(1.f + expf(-s));
  }
  __syncthreads();
  acc = cb1[tid];
  for (int d = 0; d < 256; ++d) acc = fmaf(pe[d], cw1[(size_t)tid*256 + d], acc);
  sh[tid] = fmaxf(acc, 0.f) * cw2[tid];
  __syncthreads();
  if (tid == 0) {
    float s = cb2[0];
    for (int i = 0; i < 64; ++i) s += sh[i];
    out[256 + b] = s;
  }
}

// ---------------- launch -----------------------------------------------------
extern "C" void kernel_launch(void* const* d_in, const int* in_sizes, int n_in,
                              void* d_out, int out_size, void* d_ws, size_t ws_size,
                              hipStream_t stream) {
  const float* X    = (const float*)d_in[0];
  const float* Mk   = (const float*)d_in[1];
  const float* Dl   = (const float*)d_in[2];
  const float* Tm   = (const float*)d_in[3];
  const float* Adj  = (const float*)d_in[4];
  const float* aw0  = (const float*)d_in[5];
  const float* ab0  = (const float*)d_in[6];
  const float* aWt  = (const float*)d_in[7];
  const float* aBt  = (const float*)d_in[8];
  const float* dw0  = (const float*)d_in[9];
  const float* db0  = (const float*)d_in[10];
  const float* dWt  = (const float*)d_in[11];
  const float* dBt  = (const float*)d_in[12];
  const float* gW0  = (const float*)d_in[13];
  const float* gas0 = (const float*)d_in[14];
  const float* gad0 = (const float*)d_in[15];
  const float* gW1  = (const float*)d_in[16];
  const float* gas1 = (const float*)d_in[17];
  const float* gad1 = (const float*)d_in[18];
  const float* g0f_wih = (const float*)d_in[19];
  const float* g0f_whh = (const float*)d_in[20];
  const float* g0f_bih = (const float*)d_in[21];
  const float* g0f_bhh = (const float*)d_in[22];
  const float* g0b_wih = (const float*)d_in[23];
  const float* g0b_whh = (const float*)d_in[24];
  const float* g0b_bih = (const float*)d_in[25];
  const float* g0b_bhh = (const float*)d_in[26];
  const float* g1f_wih = (const float*)d_in[27];
  const float* g1f_whh = (const float*)d_in[28];
  const float* g1f_bih = (const float*)d_in[29];
  const float* g1f_bhh = (const float*)d_in[30];
  const float* g1b_wih = (const float*)d_in[31];
  const float* g1b_whh = (const float*)d_in[32];
  const float* g1b_bih = (const float*)d_in[33];
  const float* g1b_bhh = (const float*)d_in[34];
  const float* mh_w1 = (const float*)d_in[35];
  const float* mh_b1 = (const float*)d_in[36];
  const float* mh_w2 = (const float*)d_in[37];
  const float* mh_b2 = (const float*)d_in[38];
  const float* ch_w1 = (const float*)d_in[39];
  const float* ch_b1 = (const float*)d_in[40];
  const float* ch_w2 = (const float*)d_in[41];
  const float* ch_b2 = (const float*)d_in[42];

  // workspace: gxA[12582912 bf16] | gxB[12582912 bf16] = 48 MiB
  bf16* gxA = (bf16*)d_ws;
  bf16* gxB = gxA + 12582912;

  float* out  = (float*)d_out;
  // out layout (fp32): m[128] | sig[128] | risk[128] | pemb[32768] | gru_out[B*T*256]
  float* pemb = out + 384;
  float* slot = out + 384 + 32768;     // gru_out slot, also hosts z and y

  gat_fused<<<dim3(BB*TT), dim3(256), 0, stream>>>(
      X, Mk, Dl, Tm, Adj, aw0, ab0, aWt, aBt, dw0, db0, dWt, dBt,
      gW0, gas0, gad0, gW1, gas1, gad1, slot);

  dim3 ggrid(32768/64, 384/64);
  // layer-0 input projections: A = z at slot cols 128..255 (pitch 256), K=128
  gemm_xw_bias<<<ggrid, 256, 0, stream>>>(slot + 128, 256, g0f_wih, g0f_bih, gxA, 128);
  gemm_xw_bias<<<ggrid, 256, 0, stream>>>(slot + 128, 256, g0b_wih, g0b_bih, gxB, 128);
  // layer-0 recurrence: writes y = [yf|yb] into slot (dir1 overwrites dead z)
  gru_rec<<<256, 384, 0, stream>>>(gxA, gxB, g0f_whh, g0b_whh, g0f_bhh, g0b_bhh,
                                   slot, nullptr);
  // layer-1 input projections: A = y at slot cols 0..255, K=256
  gemm_xw_bias<<<ggrid, 256, 0, stream>>>(slot, 256, g1f_wih, g1f_bih, gxA, 256);
  gemm_xw_bias<<<ggrid, 256, 0, stream>>>(slot, 256, g1b_wih, g1b_bih, gxB, 256);
  // layer-1 recurrence: writes gru_out into slot (y dead), pemb fp32
  gru_rec<<<256, 384, 0, stream>>>(gxA, gxB, g1f_whh, g1b_whh, g1f_bhh, g1b_bhh,
                                   slot, pemb);

  heads_k<<<128, 64, 0, stream>>>(pemb, mh_w1, mh_b1, mh_w2, mh_b2,
                                  ch_w1, ch_b1, ch_w2, ch_b2, out);
}

// Round 11
// 1785.662 us; speedup vs baseline: 1.9037x; 1.9037x over previous
//
#include <hip/hip_runtime.h>
#include <hip/hip_bf16.h>
#include <math.h>

// Problem constants
#define NFE 17      // graph nodes (features)
#define T2V 16      // time2vec dim
#define D0C 34      // 2 + 2*T2V
#define BB 128      // batch
#define TT 256      // seq len
#define HH 128      // GRU hidden
#define PSTR 132    // padded row stride; 132*4B=528B=33*16 -> every row 16B aligned

typedef __hip_bfloat16 bf16;
__device__ __forceinline__ float b2f(bf16 x) { return __bfloat162float(x); }

// fast transcendentals (native v_exp_f32/v_sin_f32; ~2ulp)
__device__ __forceinline__ float elu_fast(float v)  { return v > 0.f ? v : __expf(v) - 1.f; }
__device__ __forceinline__ float sigm_fast(float x) { return __fdividef(1.f, 1.f + __expf(-x)); }
__device__ __forceinline__ float tanh_fast(float x) {
  return __fdividef(2.f, 1.f + __expf(-2.f*x)) - 1.f;
}

// ---------------- GAT building blocks (per-graph, LDS resident) ----------------
// NOTE (R8/R10 lessons): inner loops need their W buffers register-resident.
// Do NOT fully unroll the 128-K loop (R8: VGPR 256 + 48 GB scratch) and do NOT
// cap VGPRs via launch_bounds min-waves (R10: VGPR 48, FETCH x70, 2.5x slower).

// layer-0 proj (17% of MACs): rows {ty,ty+8,16(pred)}, 4 cols, STEP=2 (R7-proven)
template<int D, int SSTR, int STEP>
__device__ __forceinline__ void gat_proj_rb(const float* s_src,
                                            const float* __restrict__ W,
                                            float* s_dst, int tid) {
  const int tx = (tid & 31) * 4, ty = tid >> 5;
  float acc[3][4];
  #pragma unroll
  for (int i = 0; i < 3; ++i)
    #pragma unroll
    for (int c = 0; c < 4; ++c) acc[i][c] = 0.f;
  float4 wbuf[STEP];
  #pragma unroll
  for (int s = 0; s < STEP; ++s)
    wbuf[s] = *(const float4*)&W[s*128 + tx];
  for (int d0 = 0; d0 < D; d0 += STEP) {
    float4 wcur[STEP];
    #pragma unroll
    for (int s = 0; s < STEP; ++s) wcur[s] = wbuf[s];
    if (d0 + STEP < D) {
      #pragma unroll
      for (int s = 0; s < STEP; ++s)
        wbuf[s] = *(const float4*)&W[(d0 + STEP + s)*128 + tx];
    }
    float sv[3][STEP];
    #pragma unroll
    for (int i = 0; i < 3; ++i) {
      const int r = ty + 8*i;
      if (i < 2 || ty == 0) {
        #pragma unroll
        for (int s = 0; s < STEP; ++s) sv[i][s] = s_src[r*SSTR + d0 + s];
      }
    }
    #pragma unroll
    for (int s = 0; s < STEP; ++s) {
      #pragma unroll
      for (int i = 0; i < 3; ++i) {
        if (i < 2 || ty == 0) {
          acc[i][0] = fmaf(sv[i][s], wcur[s].x, acc[i][0]);
          acc[i][1] = fmaf(sv[i][s], wcur[s].y, acc[i][1]);
          acc[i][2] = fmaf(sv[i][s], wcur[s].z, acc[i][2]);
          acc[i][3] = fmaf(sv[i][s], wcur[s].w, acc[i][3]);
        }
      }
    }
  }
  #pragma unroll
  for (int i = 0; i < 3; ++i) {
    const int r = ty + 8*i;
    if (i < 2 || ty == 0) {
      #pragma unroll
      for (int c = 0; c < 4; ++c) s_dst[r*PSTR + tx + c] = acc[i][c];
    }
  }
}

// layer-1 proj (63% of MACs): copy-free ping-pong double buffer (R9-proven).
__device__ __forceinline__ void gat_proj128_db(const float* s_src,
                                               const float* __restrict__ W,
                                               float* s_dst, int tid) {
  const int tx = (tid & 31) * 4, ty = tid >> 5;
  const int r0 = ty, r1 = ty + 8;
  float a0[4] = {0.f,0.f,0.f,0.f}, a1[4] = {0.f,0.f,0.f,0.f}, a2[4] = {0.f,0.f,0.f,0.f};
  float4 wA[4], wB[4];
  #pragma unroll
  for (int s = 0; s < 4; ++s) wA[s] = *(const float4*)&W[s*128 + tx];
  #pragma unroll 1
  for (int d0 = 0; d0 < 128; d0 += 8) {
    #pragma unroll
    for (int s = 0; s < 4; ++s) wB[s] = *(const float4*)&W[(d0 + 4 + s)*128 + tx];
    float sv0[4], sv1[4], sv2[4];
    *(float4*)sv0 = *(const float4*)&s_src[r0*PSTR + d0];
    *(float4*)sv1 = *(const float4*)&s_src[r1*PSTR + d0];
    if (ty == 0) *(float4*)sv2 = *(const float4*)&s_src[16*PSTR + d0];
    #pragma unroll
    for (int s = 0; s < 4; ++s) {
      const float4 w4 = wA[s];
      a0[0] = fmaf(sv0[s], w4.x, a0[0]); a0[1] = fmaf(sv0[s], w4.y, a0[1]);
      a0[2] = fmaf(sv0[s], w4.z, a0[2]); a0[3] = fmaf(sv0[s], w4.w, a0[3]);
      a1[0] = fmaf(sv1[s], w4.x, a1[0]); a1[1] = fmaf(sv1[s], w4.y, a1[1]);
      a1[2] = fmaf(sv1[s], w4.z, a1[2]); a1[3] = fmaf(sv1[s], w4.w, a1[3]);
      if (ty == 0) {
        a2[0] = fmaf(sv2[s], w4.x, a2[0]); a2[1] = fmaf(sv2[s], w4.y, a2[1]);
        a2[2] = fmaf(sv2[s], w4.z, a2[2]); a2[3] = fmaf(sv2[s], w4.w, a2[3]);
      }
    }
    if (d0 + 8 < 128) {
      #pragma unroll
      for (int s = 0; s < 4; ++s) wA[s] = *(const float4*)&W[(d0 + 8 + s)*128 + tx];
    }
    *(float4*)sv0 = *(const float4*)&s_src[r0*PSTR + d0 + 4];
    *(float4*)sv1 = *(const float4*)&s_src[r1*PSTR + d0 + 4];
    if (ty == 0) *(float4*)sv2 = *(const float4*)&s_src[16*PSTR + d0 + 4];
    #pragma unroll
    for (int s = 0; s < 4; ++s) {
      const float4 w4 = wB[s];
      a0[0] = fmaf(sv0[s], w4.x, a0[0]); a0[1] = fmaf(sv0[s], w4.y, a0[1]);
      a0[2] = fmaf(sv0[s], w4.z, a0[2]); a0[3] = fmaf(sv0[s], w4.w, a0[3]);
      a1[0] = fmaf(sv1[s], w4.x, a1[0]); a1[1] = fmaf(sv1[s], w4.y, a1[1]);
      a1[2] = fmaf(sv1[s], w4.z, a1[2]); a1[3] = fmaf(sv1[s], w4.w, a1[3]);
      if (ty == 0) {
        a2[0] = fmaf(sv2[s], w4.x, a2[0]); a2[1] = fmaf(sv2[s], w4.y, a2[1]);
        a2[2] = fmaf(sv2[s], w4.z, a2[2]); a2[3] = fmaf(sv2[s], w4.w, a2[3]);
      }
    }
  }
  #pragma unroll
  for (int c = 0; c < 4; ++c) {
    s_dst[r0*PSTR + tx + c] = a0[c];
    s_dst[r1*PSTR + tx + c] = a1[c];
  }
  if (ty == 0) {
    #pragma unroll
    for (int c = 0; c < 4; ++c) s_dst[16*PSTR + tx + c] = a2[c];
  }
}

__device__ __forceinline__ void gat_scores(const float* s_p,
                                           const float* __restrict__ asrc,
                                           const float* __restrict__ adst,
                                           float* s_es, float* s_ed, int tid) {
  if (tid < 2*4*NFE) {                 // 136 threads: 68 for es, 68 for ed
    const int which = tid >= 4*NFE;
    const int r = which ? tid - 4*NFE : tid;
    const int h = r / NFE, f = r - h*NFE;
    const float* av = which ? adst : asrc;
    float acc = 0.f;
    #pragma unroll
    for (int o = 0; o < 32; ++o)
      acc = fmaf(s_p[f*PSTR + h*32 + o], av[h*32 + o], acc);
    (which ? s_ed : s_es)[h*NFE + f] = acc;
  }
}

__device__ __forceinline__ void gat_softmax(const float* s_es, const float* s_ed,
                                            const float* s_adj,
                                            float* s_e, int tid) {
  if (tid < 4*NFE) {                   // one thread per (head,row)
    const int h = tid / NFE, i = tid - h*NFE;
    float row[NFE]; float mx = -1e30f;
    #pragma unroll
    for (int j = 0; j < NFE; ++j) {
      float v = -1.0e9f;
      if (s_adj[i*NFE + j] > 0.f) {
        float e = s_es[h*NFE + i] + s_ed[h*NFE + j];
        v = (e > 0.f) ? e : 0.2f*e;    // leaky_relu 0.2
      }
      row[j] = v; mx = fmaxf(mx, v);
    }
    float sum = 0.f;
    #pragma unroll
    for (int j = 0; j < NFE; ++j) { row[j] = __expf(row[j] - mx); sum += row[j]; }
    const float inv = __fdividef(1.f, sum);
    #pragma unroll
    for (int j = 0; j < NFE; ++j) s_e[(h*NFE + i)*NFE + j] = row[j]*inv;
  }
}

// layer-0 out: full store to s_dst (needed as residual + proj input)
__device__ __forceinline__ void gat_out_rb(const float* s_e, const float* s_p,
                                           const float* s_res, float* s_dst, int tid) {
  const int tx = (tid & 31) * 4, ty = tid >> 5;
  const int h = tx >> 5;               // 4 cols always within one head
  float acc[3][4];
  #pragma unroll
  for (int i = 0; i < 3; ++i)
    #pragma unroll
    for (int c = 0; c < 4; ++c) acc[i][c] = 0.f;
  for (int j = 0; j < NFE; ++j) {
    const float4 pv = *(const float4*)&s_p[j*PSTR + tx];
    #pragma unroll
    for (int i = 0; i < 3; ++i) {
      const int r = ty + 8*i;
      if (i < 2 || ty == 0) {
        const float av = s_e[(h*NFE + r)*NFE + j];
        acc[i][0] = fmaf(av, pv.x, acc[i][0]);
        acc[i][1] = fmaf(av, pv.y, acc[i][1]);
        acc[i][2] = fmaf(av, pv.z, acc[i][2]);
        acc[i][3] = fmaf(av, pv.w, acc[i][3]);
      }
    }
  }
  #pragma unroll
  for (int i = 0; i < 3; ++i) {
    const int r = ty + 8*i;
    if (i < 2 || ty == 0) {
      #pragma unroll
      for (int c = 0; c < 4; ++c) {
        float v = acc[i][c] + (s_res ? s_res[r*PSTR + tx + c] : 0.f);
        s_dst[r*PSTR + tx + c] = elu_fast(v);
      }
    }
  }
}

// layer-1 out: no s_o store — per-thread column partial sums over its rows.
__device__ __forceinline__ void gat_out_psum(const float* s_e, const float* s_p,
                                             const float* s_res, float* psum, int tid) {
  const int tx = (tid & 31) * 4, ty = tid >> 5;
  const int h = tx >> 5;
  float acc[3][4];
  #pragma unroll
  for (int i = 0; i < 3; ++i)
    #pragma unroll
    for (int c = 0; c < 4; ++c) acc[i][c] = 0.f;
  for (int j = 0; j < NFE; ++j) {
    const float4 pv = *(const float4*)&s_p[j*PSTR + tx];
    #pragma unroll
    for (int i = 0; i < 3; ++i) {
      const int r = ty + 8*i;
      if (i < 2 || ty == 0) {
        const float av = s_e[(h*NFE + r)*NFE + j];
        acc[i][0] = fmaf(av, pv.x, acc[i][0]);
        acc[i][1] = fmaf(av, pv.y, acc[i][1]);
        acc[i][2] = fmaf(av, pv.z, acc[i][2]);
        acc[i][3] = fmaf(av, pv.w, acc[i][3]);
      }
    }
  }
  #pragma unroll
  for (int c = 0; c < 4; ++c) psum[c] = 0.f;
  #pragma unroll
  for (int i = 0; i < 3; ++i) {
    const int r = ty + 8*i;
    if (i < 2 || ty == 0) {
      #pragma unroll
      for (int c = 0; c < 4; ++c)
        psum[c] += elu_fast(acc[i][c] + s_res[r*PSTR + tx + c]);
    }
  }
}

// --------------- fused featurize + GAT0 + GAT1 + node-mean -------------------
// Plain launch_bounds(256): compiler picks VGPRs (~80). LDS ~31.2 KB.
__global__ __launch_bounds__(256) void gat_fused(
    const float* __restrict__ X,  const float* __restrict__ Mk,
    const float* __restrict__ Dl, const float* __restrict__ Tm,
    const float* __restrict__ Adj,
    const float* __restrict__ aw0, const float* __restrict__ ab0,
    const float* __restrict__ aW,  const float* __restrict__ aB,
    const float* __restrict__ dw0, const float* __restrict__ db0,
    const float* __restrict__ dW,  const float* __restrict__ dB,
    const float* __restrict__ W0,  const float* __restrict__ as0,
    const float* __restrict__ ad0, const float* __restrict__ W1,
    const float* __restrict__ as1, const float* __restrict__ ad1,
    float* __restrict__ zslot)         // [B*T][256], z goes in cols 128..255
{
  __shared__ float s_nf[NFE*D0C];
  __shared__ __align__(16) float s_p [NFE*PSTR];
  __shared__ __align__(16) float s_h [NFE*PSTR];
  __shared__ __align__(16) float s_red[8*128];   // layer-1 mean partials
  __shared__ float s_e [4*NFE*NFE];
  __shared__ float s_es[4*NFE];
  __shared__ float s_ed[4*NFE];
  __shared__ float s_t [T2V];
  __shared__ float s_adj[NFE*NFE];
  const int n = blockIdx.x;            // n = b*T + t  (matches times layout)
  const int tid = threadIdx.x;

  const float tv = Tm[n];
  if (tid < T2V) {
    s_t[tid] = (tid == 0) ? fmaf(tv, aw0[0], ab0[0])
                          : __sinf(fmaf(tv, aW[tid-1], aB[tid-1]));
  }
  for (int idx = tid; idx < NFE*NFE; idx += 256) s_adj[idx] = Adj[idx];
  __syncthreads();
  // node features: [X, mask, t_emb(16), d_emb(16)]
  for (int idx = tid; idx < NFE*D0C; idx += 256) {
    const int f = idx / D0C, c = idx - f*D0C;
    float v;
    if (c == 0)            v = X [(size_t)n*NFE + f];
    else if (c == 1)       v = Mk[(size_t)n*NFE + f];
    else if (c < 2 + T2V)  v = s_t[c-2];
    else {
      const float dd = Dl[(size_t)n*NFE + f];
      const int j = c - (2 + T2V);
      v = (j == 0) ? fmaf(dd, dw0[0], db0[0])
                   : __sinf(fmaf(dd, dW[j-1], dB[j-1]));
    }
    s_nf[idx] = v;
  }
  __syncthreads();
  // GAT layer 0 (no residual)
  gat_proj_rb<D0C, D0C, 2>(s_nf, W0, s_p, tid);    __syncthreads();
  gat_scores(s_p, as0, ad0, s_es, s_ed, tid);      __syncthreads();
  gat_softmax(s_es, s_ed, s_adj, s_e, tid);        __syncthreads();
  gat_out_rb(s_e, s_p, nullptr, s_h, tid);         __syncthreads();
  // GAT layer 1 (residual) -> direct node-mean, no s_o
  gat_proj128_db(s_h, W1, s_p, tid);               __syncthreads();
  gat_scores(s_p, as1, ad1, s_es, s_ed, tid);      __syncthreads();
  gat_softmax(s_es, s_ed, s_adj, s_e, tid);        __syncthreads();
  {
    float psum[4];
    gat_out_psum(s_e, s_p, s_h, psum, tid);
    const int tx = (tid & 31) * 4, ty = tid >> 5;
    *(float4*)&s_red[ty*128 + tx] = *(float4*)psum;
    __syncthreads();
    if (tid < 128) {
      float acc = 0.f;
      #pragma unroll
      for (int k = 0; k < 8; ++k) acc += s_red[k*128 + tid];
      zslot[(size_t)n*256 + 128 + tid] = acc * (1.0f/17.0f);
    }
  }
}

// ------- GEMM: C[M,384] = A[M,K](f32, row pitch lda) * W[384,K](f32)^T + bias
// C stored bf16 (gate pre-activations; rel err 2^-9 << harness bf16 floor)
__global__ __launch_bounds__(256) void gemm_xw_bias(
    const float* __restrict__ A, int lda, const float* __restrict__ W,
    const float* __restrict__ bias, bf16* __restrict__ C, int K)
{
  __shared__ float As[16][68];   // +4 pad
  __shared__ float Ws[16][68];
  const int tid = threadIdx.x;
  const int bm0 = blockIdx.x * 64;
  const int bn0 = blockIdx.y * 64;
  const int tx = tid & 15, ty = tid >> 4;
  float acc[4][4];
  #pragma unroll
  for (int i = 0; i < 4; ++i)
    #pragma unroll
    for (int j = 0; j < 4; ++j) acc[i][j] = 0.f;
  for (int kk = 0; kk < K; kk += 16) {
    #pragma unroll
    for (int l = 0; l < 4; ++l) {
      const int lin = tid + l*256;
      const int r = lin >> 4, k = lin & 15;
      As[k][r] = A[(size_t)(bm0 + r)*lda + kk + k];
      Ws[k][r] = W[(size_t)(bn0 + r)*K + kk + k];
    }
    __syncthreads();
    #pragma unroll
    for (int k = 0; k < 16; ++k) {
      float av[4], wv[4];
      #pragma unroll
      for (int i = 0; i < 4; ++i) av[i] = As[k][ty*4 + i];
      #pragma unroll
      for (int j = 0; j < 4; ++j) wv[j] = Ws[k][tx*4 + j];
      #pragma unroll
      for (int i = 0; i < 4; ++i)
        #pragma unroll
        for (int j = 0; j < 4; ++j) acc[i][j] = fmaf(av[i], wv[j], acc[i][j]);
    }
    __syncthreads();
  }
  float bv[4];
  #pragma unroll
  for (int j = 0; j < 4; ++j) bv[j] = bias[bn0 + tx*4 + j];
  #pragma unroll
  for (int i = 0; i < 4; ++i)
    #pragma unroll
    for (int j = 0; j < 4; ++j)
      C[(size_t)(bm0 + ty*4 + i)*384 + bn0 + tx*4 + j] =
          __float2bfloat16(acc[i][j] + bv[j]);
}

// ---------------- GRU recurrence: one block per (dir, batch-row) -------------
__global__ __launch_bounds__(384, 1) void gru_rec(
    const bf16* __restrict__ gxf,      // [B][T][384] forward-dir input proj
    const bf16* __restrict__ gxb,      // [B][T][384] backward-dir input proj
    const float* __restrict__ whh_f, const float* __restrict__ whh_b,
    const float* __restrict__ bhh_f, const float* __restrict__ bhh_b,
    float* __restrict__ ys,            // [B][T][256], dir*128 col offset
    float* __restrict__ hfin)          // layer1: patient_emb f32 (or null)
{
  const int blk = blockIdx.x;
  const int dir = blk >> 7;
  const int b   = blk & 127;
  const int g   = threadIdx.x;
  const float* whh = dir ? whh_b : whh_f;
  const float* bhh = dir ? bhh_b : bhh_f;
  const bf16* gx   = (dir ? gxb : gxf) + (size_t)b*TT*384;
  __shared__ __align__(16) float s_h[HH];
  __shared__ float s_gh[3*HH];
  __shared__ float s_gx[3*HH];
  float4 w[HH/4];
  #pragma unroll
  for (int d4 = 0; d4 < HH/4; ++d4)
    w[d4] = *(const float4*)&whh[(size_t)g*HH + 4*d4];
  const float bh = bhh[g];
  float hreg = 0.f;
  if (g < HH) s_h[g] = 0.f;
  __syncthreads();
  for (int s = 0; s < TT; ++s) {
    const int t = dir ? (TT-1-s) : s;
    const float gxv = b2f(gx[(size_t)t*384 + g]);
    float acc = bh;
    const float4* h4 = (const float4*)s_h;
    #pragma unroll
    for (int d4 = 0; d4 < HH/4; ++d4) {
      const float4 hv = h4[d4];
      acc = fmaf(hv.x, w[d4].x, acc);
      acc = fmaf(hv.y, w[d4].y, acc);
      acc = fmaf(hv.z, w[d4].z, acc);
      acc = fmaf(hv.w, w[d4].w, acc);
    }
    s_gh[g] = acc;     // gh (incl. bhh)
    s_gx[g] = gxv;     // gx (incl. bih)
    __syncthreads();   // all dot-reads of s_h complete; s_gh/s_gx visible
    if (g < HH) {
      const float r  = sigm_fast(s_gx[g]    + s_gh[g]);
      const float zg = sigm_fast(s_gx[HH+g] + s_gh[HH+g]);
      const float nn = tanh_fast(s_gx[2*HH+g] + r*s_gh[2*HH+g]);
      hreg = (1.f - zg)*nn + zg*hreg;
      s_h[g] = hreg;
      ys[((size_t)b*TT + t)*256 + dir*HH + g] = hreg;
    }
    __syncthreads();   // new s_h visible before next step's dot
  }
  if (g < HH && hfin) hfin[(size_t)b*256 + dir*HH + g] = hreg;
}

// ---------------- heads ------------------------------------------------------
__global__ __launch_bounds__(64) void heads_k(
    const float* __restrict__ pemb,
    const float* __restrict__ mw1, const float* __restrict__ mb1,
    const float* __restrict__ mw2, const float* __restrict__ mb2,
    const float* __restrict__ cw1, const float* __restrict__ cb1,
    const float* __restrict__ cw2, const float* __restrict__ cb2,
    float* __restrict__ out)
{
  const int b = blockIdx.x, tid = threadIdx.x;
  __shared__ float sh[64];
  const float* pe = pemb + (size_t)b*256;
  float acc = mb1[tid];
  for (int d = 0; d < 256; ++d) acc = fmaf(pe[d], mw1[(size_t)tid*256 + d], acc);
  sh[tid] = fmaxf(acc, 0.f) * mw2[tid];
  __syncthreads();
  if (tid == 0) {
    float s = mb2[0];
    for (int i = 0; i < 64; ++i) s += sh[i];
    out[b]       = s;
    out[128 + b] = 1.f/(1.f + expf(-s));
  }
  __syncthreads();
  acc = cb1[tid];
  for (int d = 0; d < 256; ++d) acc = fmaf(pe[d], cw1[(size_t)tid*256 + d], acc);
  sh[tid] = fmaxf(acc, 0.f) * cw2[tid];
  __syncthreads();
  if (tid == 0) {
    float s = cb2[0];
    for (int i = 0; i < 64; ++i) s += sh[i];
    out[256 + b] = s;
  }
}

// ---------------- launch -----------------------------------------------------
extern "C" void kernel_launch(void* const* d_in, const int* in_sizes, int n_in,
                              void* d_out, int out_size, void* d_ws, size_t ws_size,
                              hipStream_t stream) {
  const float* X    = (const float*)d_in[0];
  const float* Mk   = (const float*)d_in[1];
  const float* Dl   = (const float*)d_in[2];
  const float* Tm   = (const float*)d_in[3];
  const float* Adj  = (const float*)d_in[4];
  const float* aw0  = (const float*)d_in[5];
  const float* ab0  = (const float*)d_in[6];
  const float* aWt  = (const float*)d_in[7];
  const float* aBt  = (const float*)d_in[8];
  const float* dw0  = (const float*)d_in[9];
  const float* db0  = (const float*)d_in[10];
  const float* dWt  = (const float*)d_in[11];
  const float* dBt  = (const float*)d_in[12];
  const float* gW0  = (const float*)d_in[13];
  const float* gas0 = (const float*)d_in[14];
  const float* gad0 = (const float*)d_in[15];
  const float* gW1  = (const float*)d_in[16];
  const float* gas1 = (const float*)d_in[17];
  const float* gad1 = (const float*)d_in[18];
  const float* g0f_wih = (const float*)d_in[19];
  const float* g0f_whh = (const float*)d_in[20];
  const float* g0f_bih = (const float*)d_in[21];
  const float* g0f_bhh = (const float*)d_in[22];
  const float* g0b_wih = (const float*)d_in[23];
  const float* g0b_whh = (const float*)d_in[24];
  const float* g0b_bih = (const float*)d_in[25];
  const float* g0b_bhh = (const float*)d_in[26];
  const float* g1f_wih = (const float*)d_in[27];
  const float* g1f_whh = (const float*)d_in[28];
  const float* g1f_bih = (const float*)d_in[29];
  const float* g1f_bhh = (const float*)d_in[30];
  const float* g1b_wih = (const float*)d_in[31];
  const float* g1b_whh = (const float*)d_in[32];
  const float* g1b_bih = (const float*)d_in[33];
  const float* g1b_bhh = (const float*)d_in[34];
  const float* mh_w1 = (const float*)d_in[35];
  const float* mh_b1 = (const float*)d_in[36];
  const float* mh_w2 = (const float*)d_in[37];
  const float* mh_b2 = (const float*)d_in[38];
  const float* ch_w1 = (const float*)d_in[39];
  const float* ch_b1 = (const float*)d_in[40];
  const float* ch_w2 = (const float*)d_in[41];
  const float* ch_b2 = (const float*)d_in[42];

  // workspace: gxA[12582912 bf16] | gxB[12582912 bf16] = 48 MiB
  bf16* gxA = (bf16*)d_ws;
  bf16* gxB = gxA + 12582912;

  float* out  = (float*)d_out;
  // out layout (fp32): m[128] | sig[128] | risk[128] | pemb[32768] | gru_out[B*T*256]
  float* pemb = out + 384;
  float* slot = out + 384 + 32768;     // gru_out slot, also hosts z and y

  gat_fused<<<dim3(BB*TT), dim3(256), 0, stream>>>(
      X, Mk, Dl, Tm, Adj, aw0, ab0, aWt, aBt, dw0, db0, dWt, dBt,
      gW0, gas0, gad0, gW1, gas1, gad1, slot);

  dim3 ggrid(32768/64, 384/64);
  // layer-0 input projections: A = z at slot cols 128..255 (pitch 256), K=128
  gemm_xw_bias<<<ggrid, 256, 0, stream>>>(slot + 128, 256, g0f_wih, g0f_bih, gxA, 128);
  gemm_xw_bias<<<ggrid, 256, 0, stream>>>(slot + 128, 256, g0b_wih, g0b_bih, gxB, 128);
  // layer-0 recurrence: writes y = [yf|yb] into slot (dir1 overwrites dead z)
  gru_rec<<<256, 384, 0, stream>>>(gxA, gxB, g0f_whh, g0b_whh, g0f_bhh, g0b_bhh,
                                   slot, nullptr);
  // layer-1 input projections: A = y at slot cols 0..255, K=256
  gemm_xw_bias<<<ggrid, 256, 0, stream>>>(slot, 256, g1f_wih, g1f_bih, gxA, 256);
  gemm_xw_bias<<<ggrid, 256, 0, stream>>>(slot, 256, g1b_wih, g1b_bih, gxB, 256);
  // layer-1 recurrence: writes gru_out into slot (y dead), pemb fp32
  gru_rec<<<256, 384, 0, stream>>>(gxA, gxB, g1f_whh, g1b_whh, g1f_bhh, g1b_bhh,
                                   slot, pemb);

  heads_k<<<128, 64, 0, stream>>>(pemb, mh_w1, mh_b1, mh_w2, mh_b2,
                                  ch_w1, ch_b1, ch_w2, ch_b2, out);
}

// Round 14
// 1649.522 us; speedup vs baseline: 2.0608x; 1.0825x over previous
//
#include <hip/hip_runtime.h>
#include <hip/hip_bf16.h>
#include <math.h>

// Problem constants
#define NFE 17      // graph nodes (features)
#define T2V 16      // time2vec dim
#define D0C 34      // 2 + 2*T2V
#define BB 128      // batch
#define TT 256      // seq len
#define HH 128      // GRU hidden
#define PSTR 132    // padded row stride; 132*4B=528B=33*16 -> every row 16B aligned

typedef __hip_bfloat16 bf16;
__device__ __forceinline__ float b2f(bf16 x) { return __bfloat162float(x); }

// MFMA fragment types (gfx950 16x16x32 bf16: 8 bf16 in / 4 f32 acc per lane)
typedef __attribute__((ext_vector_type(8))) __bf16 bfrag;
typedef __attribute__((ext_vector_type(4))) float  ffrag;

// fast transcendentals (native v_exp_f32/v_sin_f32; ~2ulp)
__device__ __forceinline__ float elu_fast(float v)  { return v > 0.f ? v : __expf(v) - 1.f; }
__device__ __forceinline__ float sigm_fast(float x) { return __fdividef(1.f, 1.f + __expf(-x)); }
__device__ __forceinline__ float tanh_fast(float x) {
  return __fdividef(2.f, 1.f + __expf(-2.f*x)) - 1.f;
}

// ---------------- GAT building blocks (per-graph, LDS resident) ----------------
// NOTE (R8/R10 lessons): inner loops need their W buffers register-resident.
// Do NOT fully unroll the 128-K loop (R8: VGPR 256 + 48 GB scratch) and do NOT
// cap VGPRs via launch_bounds min-waves (R10: VGPR 48, FETCH x70, 2.5x slower).

// layer-0 proj (17% of MACs): rows {ty,ty+8,16(pred)}, 4 cols, STEP=2 (R7-proven)
template<int D, int SSTR, int STEP>
__device__ __forceinline__ void gat_proj_rb(const float* s_src,
                                            const float* __restrict__ W,
                                            float* s_dst, int tid) {
  const int tx = (tid & 31) * 4, ty = tid >> 5;
  float acc[3][4];
  #pragma unroll
  for (int i = 0; i < 3; ++i)
    #pragma unroll
    for (int c = 0; c < 4; ++c) acc[i][c] = 0.f;
  float4 wbuf[STEP];
  #pragma unroll
  for (int s = 0; s < STEP; ++s)
    wbuf[s] = *(const float4*)&W[s*128 + tx];
  for (int d0 = 0; d0 < D; d0 += STEP) {
    float4 wcur[STEP];
    #pragma unroll
    for (int s = 0; s < STEP; ++s) wcur[s] = wbuf[s];
    if (d0 + STEP < D) {
      #pragma unroll
      for (int s = 0; s < STEP; ++s)
        wbuf[s] = *(const float4*)&W[(d0 + STEP + s)*128 + tx];
    }
    float sv[3][STEP];
    #pragma unroll
    for (int i = 0; i < 3; ++i) {
      const int r = ty + 8*i;
      if (i < 2 || ty == 0) {
        #pragma unroll
        for (int s = 0; s < STEP; ++s) sv[i][s] = s_src[r*SSTR + d0 + s];
      }
    }
    #pragma unroll
    for (int s = 0; s < STEP; ++s) {
      #pragma unroll
      for (int i = 0; i < 3; ++i) {
        if (i < 2 || ty == 0) {
          acc[i][0] = fmaf(sv[i][s], wcur[s].x, acc[i][0]);
          acc[i][1] = fmaf(sv[i][s], wcur[s].y, acc[i][1]);
          acc[i][2] = fmaf(sv[i][s], wcur[s].z, acc[i][2]);
          acc[i][3] = fmaf(sv[i][s], wcur[s].w, acc[i][3]);
        }
      }
    }
  }
  #pragma unroll
  for (int i = 0; i < 3; ++i) {
    const int r = ty + 8*i;
    if (i < 2 || ty == 0) {
      #pragma unroll
      for (int c = 0; c < 4; ++c) s_dst[r*PSTR + tx + c] = acc[i][c];
    }
  }
}

// layer-1 proj (63% of MACs): copy-free ping-pong double buffer (R9-proven).
__device__ __forceinline__ void gat_proj128_db(const float* s_src,
                                               const float* __restrict__ W,
                                               float* s_dst, int tid) {
  const int tx = (tid & 31) * 4, ty = tid >> 5;
  const int r0 = ty, r1 = ty + 8;
  float a0[4] = {0.f,0.f,0.f,0.f}, a1[4] = {0.f,0.f,0.f,0.f}, a2[4] = {0.f,0.f,0.f,0.f};
  float4 wA[4], wB[4];
  #pragma unroll
  for (int s = 0; s < 4; ++s) wA[s] = *(const float4*)&W[s*128 + tx];
  #pragma unroll 1
  for (int d0 = 0; d0 < 128; d0 += 8) {
    #pragma unroll
    for (int s = 0; s < 4; ++s) wB[s] = *(const float4*)&W[(d0 + 4 + s)*128 + tx];
    float sv0[4], sv1[4], sv2[4];
    *(float4*)sv0 = *(const float4*)&s_src[r0*PSTR + d0];
    *(float4*)sv1 = *(const float4*)&s_src[r1*PSTR + d0];
    if (ty == 0) *(float4*)sv2 = *(const float4*)&s_src[16*PSTR + d0];
    #pragma unroll
    for (int s = 0; s < 4; ++s) {
      const float4 w4 = wA[s];
      a0[0] = fmaf(sv0[s], w4.x, a0[0]); a0[1] = fmaf(sv0[s], w4.y, a0[1]);
      a0[2] = fmaf(sv0[s], w4.z, a0[2]); a0[3] = fmaf(sv0[s], w4.w, a0[3]);
      a1[0] = fmaf(sv1[s], w4.x, a1[0]); a1[1] = fmaf(sv1[s], w4.y, a1[1]);
      a1[2] = fmaf(sv1[s], w4.z, a1[2]); a1[3] = fmaf(sv1[s], w4.w, a1[3]);
      if (ty == 0) {
        a2[0] = fmaf(sv2[s], w4.x, a2[0]); a2[1] = fmaf(sv2[s], w4.y, a2[1]);
        a2[2] = fmaf(sv2[s], w4.z, a2[2]); a2[3] = fmaf(sv2[s], w4.w, a2[3]);
      }
    }
    if (d0 + 8 < 128) {
      #pragma unroll
      for (int s = 0; s < 4; ++s) wA[s] = *(const float4*)&W[(d0 + 8 + s)*128 + tx];
    }
    *(float4*)sv0 = *(const float4*)&s_src[r0*PSTR + d0 + 4];
    *(float4*)sv1 = *(const float4*)&s_src[r1*PSTR + d0 + 4];
    if (ty == 0) *(float4*)sv2 = *(const float4*)&s_src[16*PSTR + d0 + 4];
    #pragma unroll
    for (int s = 0; s < 4; ++s) {
      const float4 w4 = wB[s];
      a0[0] = fmaf(sv0[s], w4.x, a0[0]); a0[1] = fmaf(sv0[s], w4.y, a0[1]);
      a0[2] = fmaf(sv0[s], w4.z, a0[2]); a0[3] = fmaf(sv0[s], w4.w, a0[3]);
      a1[0] = fmaf(sv1[s], w4.x, a1[0]); a1[1] = fmaf(sv1[s], w4.y, a1[1]);
      a1[2] = fmaf(sv1[s], w4.z, a1[2]); a1[3] = fmaf(sv1[s], w4.w, a1[3]);
      if (ty == 0) {
        a2[0] = fmaf(sv2[s], w4.x, a2[0]); a2[1] = fmaf(sv2[s], w4.y, a2[1]);
        a2[2] = fmaf(sv2[s], w4.z, a2[2]); a2[3] = fmaf(sv2[s], w4.w, a2[3]);
      }
    }
  }
  #pragma unroll
  for (int c = 0; c < 4; ++c) {
    s_dst[r0*PSTR + tx + c] = a0[c];
    s_dst[r1*PSTR + tx + c] = a1[c];
  }
  if (ty == 0) {
    #pragma unroll
    for (int c = 0; c < 4; ++c) s_dst[16*PSTR + tx + c] = a2[c];
  }
}

__device__ __forceinline__ void gat_scores(const float* s_p,
                                           const float* __restrict__ asrc,
                                           const float* __restrict__ adst,
                                           float* s_es, float* s_ed, int tid) {
  if (tid < 2*4*NFE) {                 // 136 threads: 68 for es, 68 for ed
    const int which = tid >= 4*NFE;
    const int r = which ? tid - 4*NFE : tid;
    const int h = r / NFE, f = r - h*NFE;
    const float* av = which ? adst : asrc;
    float acc = 0.f;
    #pragma unroll
    for (int o = 0; o < 32; ++o)
      acc = fmaf(s_p[f*PSTR + h*32 + o], av[h*32 + o], acc);
    (which ? s_ed : s_es)[h*NFE + f] = acc;
  }
}

__device__ __forceinline__ void gat_softmax(const float* s_es, const float* s_ed,
                                            const float* s_adj,
                                            float* s_e, int tid) {
  if (tid < 4*NFE) {                   // one thread per (head,row)
    const int h = tid / NFE, i = tid - h*NFE;
    float row[NFE]; float mx = -1e30f;
    #pragma unroll
    for (int j = 0; j < NFE; ++j) {
      float v = -1.0e9f;
      if (s_adj[i*NFE + j] > 0.f) {
        float e = s_es[h*NFE + i] + s_ed[h*NFE + j];
        v = (e > 0.f) ? e : 0.2f*e;    // leaky_relu 0.2
      }
      row[j] = v; mx = fmaxf(mx, v);
    }
    float sum = 0.f;
    #pragma unroll
    for (int j = 0; j < NFE; ++j) { row[j] = __expf(row[j] - mx); sum += row[j]; }
    const float inv = __fdividef(1.f, sum);
    #pragma unroll
    for (int j = 0; j < NFE; ++j) s_e[(h*NFE + i)*NFE + j] = row[j]*inv;
  }
}

// layer-0 out: full store to s_dst (needed as residual + proj input)
__device__ __forceinline__ void gat_out_rb(const float* s_e, const float* s_p,
                                           const float* s_res, float* s_dst, int tid) {
  const int tx = (tid & 31) * 4, ty = tid >> 5;
  const int h = tx >> 5;               // 4 cols always within one head
  float acc[3][4];
  #pragma unroll
  for (int i = 0; i < 3; ++i)
    #pragma unroll
    for (int c = 0; c < 4; ++c) acc[i][c] = 0.f;
  for (int j = 0; j < NFE; ++j) {
    const float4 pv = *(const float4*)&s_p[j*PSTR + tx];
    #pragma unroll
    for (int i = 0; i < 3; ++i) {
      const int r = ty + 8*i;
      if (i < 2 || ty == 0) {
        const float av = s_e[(h*NFE + r)*NFE + j];
        acc[i][0] = fmaf(av, pv.x, acc[i][0]);
        acc[i][1] = fmaf(av, pv.y, acc[i][1]);
        acc[i][2] = fmaf(av, pv.z, acc[i][2]);
        acc[i][3] = fmaf(av, pv.w, acc[i][3]);
      }
    }
  }
  #pragma unroll
  for (int i = 0; i < 3; ++i) {
    const int r = ty + 8*i;
    if (i < 2 || ty == 0) {
      #pragma unroll
      for (int c = 0; c < 4; ++c) {
        float v = acc[i][c] + (s_res ? s_res[r*PSTR + tx + c] : 0.f);
        s_dst[r*PSTR + tx + c] = elu_fast(v);
      }
    }
  }
}

// layer-1 out: no s_o store — per-thread column partial sums over its rows.
__device__ __forceinline__ void gat_out_psum(const float* s_e, const float* s_p,
                                             const float* s_res, float* psum, int tid) {
  const int tx = (tid & 31) * 4, ty = tid >> 5;
  const int h = tx >> 5;
  float acc[3][4];
  #pragma unroll
  for (int i = 0; i < 3; ++i)
    #pragma unroll
    for (int c = 0; c < 4; ++c) acc[i][c] = 0.f;
  for (int j = 0; j < NFE; ++j) {
    const float4 pv = *(const float4*)&s_p[j*PSTR + tx];
    #pragma unroll
    for (int i = 0; i < 3; ++i) {
      const int r = ty + 8*i;
      if (i < 2 || ty == 0) {
        const float av = s_e[(h*NFE + r)*NFE + j];
        acc[i][0] = fmaf(av, pv.x, acc[i][0]);
        acc[i][1] = fmaf(av, pv.y, acc[i][1]);
        acc[i][2] = fmaf(av, pv.z, acc[i][2]);
        acc[i][3] = fmaf(av, pv.w, acc[i][3]);
      }
    }
  }
  #pragma unroll
  for (int c = 0; c < 4; ++c) psum[c] = 0.f;
  #pragma unroll
  for (int i = 0; i < 3; ++i) {
    const int r = ty + 8*i;
    if (i < 2 || ty == 0) {
      #pragma unroll
      for (int c = 0; c < 4; ++c)
        psum[c] += elu_fast(acc[i][c] + s_res[r*PSTR + tx + c]);
    }
  }
}

// --------------- fused featurize + GAT0 + GAT1 + node-mean -------------------
// Plain launch_bounds(256): compiler picks VGPRs (~80). LDS ~31.2 KB.
__global__ __launch_bounds__(256) void gat_fused(
    const float* __restrict__ X,  const float* __restrict__ Mk,
    const float* __restrict__ Dl, const float* __restrict__ Tm,
    const float* __restrict__ Adj,
    const float* __restrict__ aw0, const float* __restrict__ ab0,
    const float* __restrict__ aW,  const float* __restrict__ aB,
    const float* __restrict__ dw0, const float* __restrict__ db0,
    const float* __restrict__ dW,  const float* __restrict__ dB,
    const float* __restrict__ W0,  const float* __restrict__ as0,
    const float* __restrict__ ad0, const float* __restrict__ W1,
    const float* __restrict__ as1, const float* __restrict__ ad1,
    float* __restrict__ zslot)         // [B*T][256], z goes in cols 128..255
{
  __shared__ float s_nf[NFE*D0C];
  __shared__ __align__(16) float s_p [NFE*PSTR];
  __shared__ __align__(16) float s_h [NFE*PSTR];
  __shared__ __align__(16) float s_red[8*128];   // layer-1 mean partials
  __shared__ float s_e [4*NFE*NFE];
  __shared__ float s_es[4*NFE];
  __shared__ float s_ed[4*NFE];
  __shared__ float s_t [T2V];
  __shared__ float s_adj[NFE*NFE];
  const int n = blockIdx.x;            // n = b*T + t  (matches times layout)
  const int tid = threadIdx.x;

  const float tv = Tm[n];
  if (tid < T2V) {
    s_t[tid] = (tid == 0) ? fmaf(tv, aw0[0], ab0[0])
                          : __sinf(fmaf(tv, aW[tid-1], aB[tid-1]));
  }
  for (int idx = tid; idx < NFE*NFE; idx += 256) s_adj[idx] = Adj[idx];
  __syncthreads();
  // node features: [X, mask, t_emb(16), d_emb(16)]
  for (int idx = tid; idx < NFE*D0C; idx += 256) {
    const int f = idx / D0C, c = idx - f*D0C;
    float v;
    if (c == 0)            v = X [(size_t)n*NFE + f];
    else if (c == 1)       v = Mk[(size_t)n*NFE + f];
    else if (c < 2 + T2V)  v = s_t[c-2];
    else {
      const float dd = Dl[(size_t)n*NFE + f];
      const int j = c - (2 + T2V);
      v = (j == 0) ? fmaf(dd, dw0[0], db0[0])
                   : __sinf(fmaf(dd, dW[j-1], dB[j-1]));
    }
    s_nf[idx] = v;
  }
  __syncthreads();
  // GAT layer 0 (no residual)
  gat_proj_rb<D0C, D0C, 2>(s_nf, W0, s_p, tid);    __syncthreads();
  gat_scores(s_p, as0, ad0, s_es, s_ed, tid);      __syncthreads();
  gat_softmax(s_es, s_ed, s_adj, s_e, tid);        __syncthreads();
  gat_out_rb(s_e, s_p, nullptr, s_h, tid);         __syncthreads();
  // GAT layer 1 (residual) -> direct node-mean, no s_o
  gat_proj128_db(s_h, W1, s_p, tid);               __syncthreads();
  gat_scores(s_p, as1, ad1, s_es, s_ed, tid);      __syncthreads();
  gat_softmax(s_es, s_ed, s_adj, s_e, tid);        __syncthreads();
  {
    float psum[4];
    gat_out_psum(s_e, s_p, s_h, psum, tid);
    const int tx = (tid & 31) * 4, ty = tid >> 5;
    *(float4*)&s_red[ty*128 + tx] = *(float4*)psum;
    __syncthreads();
    if (tid < 128) {
      float acc = 0.f;
      #pragma unroll
      for (int k = 0; k < 8; ++k) acc += s_red[k*128 + tid];
      zslot[(size_t)n*256 + 128 + tid] = acc * (1.0f/17.0f);
    }
  }
}

// ------- MFMA GEMM (full split-precision): C = A(f32)*W(f32)^T + bias
// A = Ahi+Alo, W = Whi+Wlo (bf16 pairs). C ≈ Alo*Whi + Ahi*Wlo + Ahi*Whi
// (Alo*Wlo ~2^-18 dropped) -> ~fp32 accuracy. Inputs are FULL fp32 (R13
// post-mortem: W is NOT pre-bf16-rounded — both operands must be split).
// Fragment layouts (HW-verified, guide m89/m91):
//   A-frag: A[m=lane&15][k=quad*8+j]   B-frag: W[n=lane&15][k=quad*8+j]
//   C/D   : col(n)=lane&15, row(m)=quad*4+reg
__global__ __launch_bounds__(256) void gemm_xw_mfma(
    const float* __restrict__ A, int lda, const float* __restrict__ W,
    const float* __restrict__ bias, bf16* __restrict__ C, int K)
{
  __shared__ __bf16 Ah[64][40];   // pad 32->40: row = 80 B (16B-aligned)
  __shared__ __bf16 Al[64][40];
  __shared__ __bf16 Wh[64][40];
  __shared__ __bf16 Wl[64][40];
  const int tid = threadIdx.x;
  const int bm0 = blockIdx.x * 64;
  const int bn0 = blockIdx.y * 64;
  const int lane = tid & 63, wv = tid >> 6;
  const int mn = lane & 15, q = lane >> 4;
  const int sr = tid >> 2, sk = (tid & 3) * 8;   // staging: row, k-offset
  ffrag acc[4] = {};
  for (int kk = 0; kk < K; kk += 32) {
    // stage A and W chunks, each split hi/lo; coalesced float4 reads
    {
      float av[8];
      *(float4*)&av[0] = *(const float4*)&A[(size_t)(bm0 + sr)*lda + kk + sk];
      *(float4*)&av[4] = *(const float4*)&A[(size_t)(bm0 + sr)*lda + kk + sk + 4];
      __bf16 th[8], tl[8];
      #pragma unroll
      for (int i = 0; i < 8; ++i) {
        const __bf16 hi = (__bf16)av[i];
        th[i] = hi;
        tl[i] = (__bf16)(av[i] - (float)hi);
      }
      *(bfrag*)&Ah[sr][sk] = *(bfrag*)th;
      *(bfrag*)&Al[sr][sk] = *(bfrag*)tl;
      float wv8[8];
      *(float4*)&wv8[0] = *(const float4*)&W[(size_t)(bn0 + sr)*K + kk + sk];
      *(float4*)&wv8[4] = *(const float4*)&W[(size_t)(bn0 + sr)*K + kk + sk + 4];
      __bf16 wh8[8], wl8[8];
      #pragma unroll
      for (int i = 0; i < 8; ++i) {
        const __bf16 hi = (__bf16)wv8[i];
        wh8[i] = hi;
        wl8[i] = (__bf16)(wv8[i] - (float)hi);
      }
      *(bfrag*)&Wh[sr][sk] = *(bfrag*)wh8;
      *(bfrag*)&Wl[sr][sk] = *(bfrag*)wl8;
    }
    __syncthreads();
    const bfrag afh = *(const bfrag*)&Ah[16*wv + mn][q*8];
    const bfrag afl = *(const bfrag*)&Al[16*wv + mn][q*8];
    #pragma unroll
    for (int t = 0; t < 4; ++t) {
      const bfrag bwh = *(const bfrag*)&Wh[16*t + mn][q*8];
      const bfrag bwl = *(const bfrag*)&Wl[16*t + mn][q*8];
      acc[t] = __builtin_amdgcn_mfma_f32_16x16x32_bf16(afl, bwh, acc[t], 0, 0, 0);
      acc[t] = __builtin_amdgcn_mfma_f32_16x16x32_bf16(afh, bwl, acc[t], 0, 0, 0);
      acc[t] = __builtin_amdgcn_mfma_f32_16x16x32_bf16(afh, bwh, acc[t], 0, 0, 0);
    }
    __syncthreads();
  }
  // epilogue: C[m][n] = acc + bias
  #pragma unroll
  for (int t = 0; t < 4; ++t) {
    const int col = bn0 + 16*t + mn;
    const float bv = bias[col];
    #pragma unroll
    for (int i = 0; i < 4; ++i) {
      const int row = bm0 + 16*wv + q*4 + i;
      C[(size_t)row*384 + col] = __float2bfloat16(acc[t][i] + bv);
    }
  }
}

// ---------------- GRU recurrence: one block per (dir, batch-row) -------------
__global__ __launch_bounds__(384, 1) void gru_rec(
    const bf16* __restrict__ gxf,      // [B][T][384] forward-dir input proj
    const bf16* __restrict__ gxb,      // [B][T][384] backward-dir input proj
    const float* __restrict__ whh_f, const float* __restrict__ whh_b,
    const float* __restrict__ bhh_f, const float* __restrict__ bhh_b,
    float* __restrict__ ys,            // [B][T][256], dir*128 col offset
    float* __restrict__ hfin)          // layer1: patient_emb f32 (or null)
{
  const int blk = blockIdx.x;
  const int dir = blk >> 7;
  const int b   = blk & 127;
  const int g   = threadIdx.x;
  const float* whh = dir ? whh_b : whh_f;
  const float* bhh = dir ? bhh_b : bhh_f;
  const bf16* gx   = (dir ? gxb : gxf) + (size_t)b*TT*384;
  __shared__ __align__(16) float s_h[HH];
  __shared__ float s_gh[3*HH];
  __shared__ float s_gx[3*HH];
  float4 w[HH/4];
  #pragma unroll
  for (int d4 = 0; d4 < HH/4; ++d4)
    w[d4] = *(const float4*)&whh[(size_t)g*HH + 4*d4];
  const float bh = bhh[g];
  float hreg = 0.f;
  if (g < HH) s_h[g] = 0.f;
  __syncthreads();
  for (int s = 0; s < TT; ++s) {
    const int t = dir ? (TT-1-s) : s;
    const float gxv = b2f(gx[(size_t)t*384 + g]);
    float acc = bh;
    const float4* h4 = (const float4*)s_h;
    #pragma unroll
    for (int d4 = 0; d4 < HH/4; ++d4) {
      const float4 hv = h4[d4];
      acc = fmaf(hv.x, w[d4].x, acc);
      acc = fmaf(hv.y, w[d4].y, acc);
      acc = fmaf(hv.z, w[d4].z, acc);
      acc = fmaf(hv.w, w[d4].w, acc);
    }
    s_gh[g] = acc;     // gh (incl. bhh)
    s_gx[g] = gxv;     // gx (incl. bih)
    __syncthreads();   // all dot-reads of s_h complete; s_gh/s_gx visible
    if (g < HH) {
      const float r  = sigm_fast(s_gx[g]    + s_gh[g]);
      const float zg = sigm_fast(s_gx[HH+g] + s_gh[HH+g]);
      const float nn = tanh_fast(s_gx[2*HH+g] + r*s_gh[2*HH+g]);
      hreg = (1.f - zg)*nn + zg*hreg;
      s_h[g] = hreg;
      ys[((size_t)b*TT + t)*256 + dir*HH + g] = hreg;
    }
    __syncthreads();   // new s_h visible before next step's dot
  }
  if (g < HH && hfin) hfin[(size_t)b*256 + dir*HH + g] = hreg;
}

// ---------------- heads ------------------------------------------------------
__global__ __launch_bounds__(64) void heads_k(
    const float* __restrict__ pemb,
    const float* __restrict__ mw1, const float* __restrict__ mb1,
    const float* __restrict__ mw2, const float* __restrict__ mb2,
    const float* __restrict__ cw1, const float* __restrict__ cb1,
    const float* __restrict__ cw2, const float* __restrict__ cb2,
    float* __restrict__ out)
{
  const int b = blockIdx.x, tid = threadIdx.x;
  __shared__ float sh[64];
  const float* pe = pemb + (size_t)b*256;
  float acc = mb1[tid];
  for (int d = 0; d < 256; ++d) acc = fmaf(pe[d], mw1[(size_t)tid*256 + d], acc);
  sh[tid] = fmaxf(acc, 0.f) * mw2[tid];
  __syncthreads();
  if (tid == 0) {
    float s = mb2[0];
    for (int i = 0; i < 64; ++i) s += sh[i];
    out[b]       = s;
    out[128 + b] = 1.f/(1.f + expf(-s));
  }
  __syncthreads();
  acc = cb1[tid];
  for (int d = 0; d < 256; ++d) acc = fmaf(pe[d], cw1[(size_t)tid*256 + d], acc);
  sh[tid] = fmaxf(acc, 0.f) * cw2[tid];
  __syncthreads();
  if (tid == 0) {
    float s = cb2[0];
    for (int i = 0; i < 64; ++i) s += sh[i];
    out[256 + b] = s;
  }
}

// ---------------- launch -----------------------------------------------------
extern "C" void kernel_launch(void* const* d_in, const int* in_sizes, int n_in,
                              void* d_out, int out_size, void* d_ws, size_t ws_size,
                              hipStream_t stream) {
  const float* X    = (const float*)d_in[0];
  const float* Mk   = (const float*)d_in[1];
  const float* Dl   = (const float*)d_in[2];
  const float* Tm   = (const float*)d_in[3];
  const float* Adj  = (const float*)d_in[4];
  const float* aw0  = (const float*)d_in[5];
  const float* ab0  = (const float*)d_in[6];
  const float* aWt  = (const float*)d_in[7];
  const float* aBt  = (const float*)d_in[8];
  const float* dw0  = (const float*)d_in[9];
  const float* db0  = (const float*)d_in[10];
  const float* dWt  = (const float*)d_in[11];
  const float* dBt  = (const float*)d_in[12];
  const float* gW0  = (const float*)d_in[13];
  const float* gas0 = (const float*)d_in[14];
  const float* gad0 = (const float*)d_in[15];
  const float* gW1  = (const float*)d_in[16];
  const float* gas1 = (const float*)d_in[17];
  const float* gad1 = (const float*)d_in[18];
  const float* g0f_wih = (const float*)d_in[19];
  const float* g0f_whh = (const float*)d_in[20];
  const float* g0f_bih = (const float*)d_in[21];
  const float* g0f_bhh = (const float*)d_in[22];
  const float* g0b_wih = (const float*)d_in[23];
  const float* g0b_whh = (const float*)d_in[24];
  const float* g0b_bih = (const float*)d_in[25];
  const float* g0b_bhh = (const float*)d_in[26];
  const float* g1f_wih = (const float*)d_in[27];
  const float* g1f_whh = (const float*)d_in[28];
  const float* g1f_bih = (const float*)d_in[29];
  const float* g1f_bhh = (const float*)d_in[30];
  const float* g1b_wih = (const float*)d_in[31];
  const float* g1b_whh = (const float*)d_in[32];
  const float* g1b_bih = (const float*)d_in[33];
  const float* g1b_bhh = (const float*)d_in[34];
  const float* mh_w1 = (const float*)d_in[35];
  const float* mh_b1 = (const float*)d_in[36];
  const float* mh_w2 = (const float*)d_in[37];
  const float* mh_b2 = (const float*)d_in[38];
  const float* ch_w1 = (const float*)d_in[39];
  const float* ch_b1 = (const float*)d_in[40];
  const float* ch_w2 = (const float*)d_in[41];
  const float* ch_b2 = (const float*)d_in[42];

  // workspace: gxA[12582912 bf16] | gxB[12582912 bf16] = 48 MiB
  bf16* gxA = (bf16*)d_ws;
  bf16* gxB = gxA + 12582912;

  float* out  = (float*)d_out;
  // out layout (fp32): m[128] | sig[128] | risk[128] | pemb[32768] | gru_out[B*T*256]
  float* pemb = out + 384;
  float* slot = out + 384 + 32768;     // gru_out slot, also hosts z and y

  gat_fused<<<dim3(BB*TT), dim3(256), 0, stream>>>(
      X, Mk, Dl, Tm, Adj, aw0, ab0, aWt, aBt, dw0, db0, dWt, dBt,
      gW0, gas0, gad0, gW1, gas1, gad1, slot);

  dim3 ggrid(32768/64, 384/64);
  // layer-0 input projections: A = z at slot cols 128..255 (pitch 256), K=128
  gemm_xw_mfma<<<ggrid, 256, 0, stream>>>(slot + 128, 256, g0f_wih, g0f_bih, gxA, 128);
  gemm_xw_mfma<<<ggrid, 256, 0, stream>>>(slot + 128, 256, g0b_wih, g0b_bih, gxB, 128);
  // layer-0 recurrence: writes y = [yf|yb] into slot (dir1 overwrites dead z)
  gru_rec<<<256, 384, 0, stream>>>(gxA, gxB, g0f_whh, g0b_whh, g0f_bhh, g0b_bhh,
                                   slot, nullptr);
  // layer-1 input projections: A = y at slot cols 0..255, K=256
  gemm_xw_mfma<<<ggrid, 256, 0, stream>>>(slot, 256, g1f_wih, g1f_bih, gxA, 256);
  gemm_xw_mfma<<<ggrid, 256, 0, stream>>>(slot, 256, g1b_wih, g1b_bih, gxB, 256);
  // layer-1 recurrence: writes gru_out into slot (y dead), pemb fp32
  gru_rec<<<256, 384, 0, stream>>>(gxA, gxB, g1f_whh, g1b_whh, g1f_bhh, g1b_bhh,
                                   slot, pemb);

  heads_k<<<128, 64, 0, stream>>>(pemb, mh_w1, mh_b1, mh_w2, mh_b2,
                                  ch_w1, ch_b1, ch_w2, ch_b2, out);
}